// Round 8
// baseline (238.992 us; speedup 1.0000x reference)
//
#include <hip/hip_runtime.h>
#include <hip/hip_bf16.h>
#include <cstdint>

typedef __bf16 bf16_t;
typedef __bf16 bf16x8 __attribute__((ext_vector_type(8)));
typedef float  f32x4  __attribute__((ext_vector_type(4)));

#define MFMA16(a, b, c) __builtin_amdgcn_mfma_f32_16x16x32_bf16((a), (b), (c), 0, 0, 0)

constexpr int BB = 8, CC = 384, NHH = 6, TT = 1024;
constexpr int NGQ = NHH * TT;

union U8 { uint4 u; bf16_t h[8]; };
union U2 { unsigned int u; bf16_t h[2]; };

// ---------------------------------------------------------------------------
// K0: normalize all inputs to canonical bf16 (inputs fp32; probe kept).
// ---------------------------------------------------------------------------
struct CastArgs {
    const void* src[9];
    bf16_t*     dst[9];
    int         n[9];
};

__global__ __launch_bounds__(256) void cast_kernel(CastArgs a)
{
    const bool isbf = (((const unsigned short*)a.src[5])[0] == 0x3F80u);
    const int ai = blockIdx.y;
    const int n  = a.n[ai];
    bf16_t* dst  = a.dst[ai];
    const int t0     = (blockIdx.x * 256 + threadIdx.x) * 8;
    const int stride = gridDim.x * 256 * 8;
    if (isbf) {
        const bf16_t* s = (const bf16_t*)a.src[ai];
        for (int idx = t0; idx < n; idx += stride) {
            if (idx + 8 <= n) *(uint4*)(dst + idx) = *(const uint4*)(s + idx);
            else for (int j = 0; idx + j < n; ++j) dst[idx + j] = s[idx + j];
        }
    } else {
        const float* s = (const float*)a.src[ai];
        for (int idx = t0; idx < n; idx += stride) {
            if (idx + 8 <= n) {
                f32x4 v0 = *(const f32x4*)(s + idx);
                f32x4 v1 = *(const f32x4*)(s + idx + 4);
                U8 o;
                #pragma unroll
                for (int j = 0; j < 4; ++j) { o.h[j] = (bf16_t)v0[j]; o.h[4 + j] = (bf16_t)v1[j]; }
                *(uint4*)(dst + idx) = o.u;
            } else for (int j = 0; idx + j < n; ++j) dst[idx + j] = (bf16_t)s[idx + j];
        }
    }
}

// ---------------------------------------------------------------------------
// K1: QKV projection.  q/k branch: A=W (D rows = o, regs span 4 consecutive o)
// so qT/kT stores pack as b64 into the o-contiguous [t][o] layout.
// v branch: A=xT (regs span t) packs into the t-contiguous vm[o][t] layout.
// ---------------------------------------------------------------------------
__global__ __launch_bounds__(256) void qkv_kernel(
    const bf16_t* __restrict__ x,
    const bf16_t* __restrict__ Wq,
    const bf16_t* __restrict__ Wk,
    const bf16_t* __restrict__ Wv,
    bf16_t* __restrict__ qT,
    bf16_t* __restrict__ kT,
    bf16_t* __restrict__ vm)
{
    const int og = blockIdx.x;        // 0,1:q  2,3:k  4,5:v
    const int tt = blockIdx.y;
    const int b  = blockIdx.z;
    const int t0 = tt * 64;
    const int tid  = threadIdx.x;
    const int lane = tid & 63;
    const int wid  = tid >> 6;
    const int quad = lane >> 4;
    const int l16  = lane & 15;

    __shared__ __align__(16) bf16_t xT[64][CC + 8];

    {
        const bf16_t* xb = x + (size_t)b * CC * TT;
        const int tq = tid & 7;
        const int cp = tid >> 3;
        #pragma unroll
        for (int pass = 0; pass < 6; ++pass) {
            const int c = (pass * 32 + cp) * 2;
            U8 r0, r1;
            r0.u = *(const uint4*)(xb + (size_t)c * TT + t0 + tq * 8);
            r1.u = *(const uint4*)(xb + (size_t)(c + 1) * TT + t0 + tq * 8);
            #pragma unroll
            for (int j = 0; j < 8; ++j) {
                U2 p; p.h[0] = r0.h[j]; p.h[1] = r1.h[j];
                *(unsigned int*)&xT[tq * 8 + j][c] = p.u;
            }
        }
    }
    __syncthreads();

    const bf16_t* W = (og < 2) ? Wq : (og < 4) ? Wk : Wv;
    const int obase = (og & 1) * 192 + wid * 48;

    if (og < 4) {
        // A = W rows (m=o, 3 groups), B = xT rows (n=t, 4 groups)
        f32x4 acc[3][4];
        const f32x4 zero = {0.f, 0.f, 0.f, 0.f};
        #pragma unroll
        for (int mi = 0; mi < 3; ++mi)
            #pragma unroll
            for (int ni = 0; ni < 4; ++ni) acc[mi][ni] = zero;

        for (int k0 = 0; k0 < CC; k0 += 32) {
            bf16x8 afr[3];
            #pragma unroll
            for (int mi = 0; mi < 3; ++mi)
                afr[mi] = *(const bf16x8*)(W + (size_t)(obase + mi * 16 + l16) * CC + k0 + quad * 8);
            #pragma unroll
            for (int ni = 0; ni < 4; ++ni) {
                bf16x8 bfr = *(const bf16x8*)&xT[ni * 16 + l16][k0 + quad * 8];
                #pragma unroll
                for (int mi = 0; mi < 3; ++mi)
                    acc[mi][ni] = MFMA16(afr[mi], bfr, acc[mi][ni]);
            }
        }

        bf16_t* dst = (og < 2) ? qT : kT;
        #pragma unroll
        for (int mi = 0; mi < 3; ++mi)
            #pragma unroll
            for (int ni = 0; ni < 4; ++ni) {
                const int o0 = obase + mi * 16 + quad * 4;
                const int tl = t0 + ni * 16 + l16;
                U2 lo2, hi2;
                lo2.h[0] = (bf16_t)acc[mi][ni][0]; lo2.h[1] = (bf16_t)acc[mi][ni][1];
                hi2.h[0] = (bf16_t)acc[mi][ni][2]; hi2.h[1] = (bf16_t)acc[mi][ni][3];
                uint2 pk; pk.x = lo2.u; pk.y = hi2.u;
                *(uint2*)(dst + ((size_t)b * TT + tl) * CC + o0) = pk;
            }
    } else {
        // A = xT (m=t), B = W (n=o): regs span t -> pack into vm[o][t]
        f32x4 acc[4][3];
        const f32x4 zero = {0.f, 0.f, 0.f, 0.f};
        #pragma unroll
        for (int mi = 0; mi < 4; ++mi)
            #pragma unroll
            for (int ni = 0; ni < 3; ++ni) acc[mi][ni] = zero;

        for (int k0 = 0; k0 < CC; k0 += 32) {
            bf16x8 bfr[3];
            #pragma unroll
            for (int ni = 0; ni < 3; ++ni)
                bfr[ni] = *(const bf16x8*)(W + (size_t)(obase + ni * 16 + l16) * CC + k0 + quad * 8);
            #pragma unroll
            for (int mi = 0; mi < 4; ++mi) {
                bf16x8 afr = *(const bf16x8*)&xT[mi * 16 + l16][k0 + quad * 8];
                #pragma unroll
                for (int ni = 0; ni < 3; ++ni)
                    acc[mi][ni] = MFMA16(afr, bfr[ni], acc[mi][ni]);
            }
        }

        #pragma unroll
        for (int mi = 0; mi < 4; ++mi)
            #pragma unroll
            for (int ni = 0; ni < 3; ++ni) {
                const int ol  = obase + ni * 16 + l16;
                const int tl0 = mi * 16 + quad * 4;
                U2 lo2, hi2;
                lo2.h[0] = (bf16_t)acc[mi][ni][0]; lo2.h[1] = (bf16_t)acc[mi][ni][1];
                hi2.h[0] = (bf16_t)acc[mi][ni][2]; hi2.h[1] = (bf16_t)acc[mi][ni][3];
                uint2 pk; pk.x = lo2.u; pk.y = hi2.u;
                *(uint2*)(vm + ((size_t)b * CC + ol) * TT + t0 + tl0) = pk;
            }
    }
}

// ---------------------------------------------------------------------------
// K1b: vrs[b][g][d] = sum_t vm[b][g*64+d][t]
// ---------------------------------------------------------------------------
__global__ __launch_bounds__(256) void vrow_kernel(const bf16_t* __restrict__ vm,
                                                   float* __restrict__ vrs)
{
    const int bg = blockIdx.x;
    const int d  = threadIdx.x & 63;
    const int qr = threadIdx.x >> 6;
    const bf16_t* row = vm + ((size_t)(bg / 6) * CC + (bg % 6) * 64 + d) * TT + qr * 256;
    float s = 0.f;
    for (int i = 0; i < 256; i += 8) {
        U8 v; v.u = *(const uint4*)(row + i);
        #pragma unroll
        for (int j = 0; j < 8; ++j) s += (float)v.h[j];
    }
    __shared__ float red[4][64];
    red[qr][d] = s;
    __syncthreads();
    if (qr == 0) vrs[bg * 64 + d] = red[0][d] + red[1][d] + red[2][d] + red[3][d];
}

// ---------------------------------------------------------------------------
// K1c: Qmix[(b*6+g)][q][c] = qT[b][q][c] * (0.125*head_w[g][c/64])
// One pass over q for all 6 g -> score's B-stage becomes a pure copy.
// ---------------------------------------------------------------------------
__global__ __launch_bounds__(256) void qmix_kernel(
    const bf16_t* __restrict__ qT,
    const bf16_t* __restrict__ head_w,
    bf16_t* __restrict__ Qmix)
{
    const int bg = blockIdx.x;          // b*6+g
    const int qc = blockIdx.y;          // 16 chunks of 64 q rows
    const int b  = bg / 6, g = bg % 6;
    const int tid = threadIdx.x;

    float smix6[6];
    #pragma unroll
    for (int h = 0; h < 6; ++h) smix6[h] = 0.125f * (float)head_w[g * 6 + h];

    const bf16_t* src = qT   + ((size_t)b * TT + qc * 64) * CC;
    bf16_t*       dst = Qmix + ((size_t)bg * TT + qc * 64) * CC;
    #pragma unroll
    for (int it = 0; it < 12; ++it) {
        const int idx = (it * 256 + tid) * 8;   // < 64*384
        U8 v; v.u = *(const uint4*)(src + idx);
        const float m = smix6[(idx % CC) >> 6];
        U8 o;
        #pragma unroll
        for (int j = 0; j < 8; ++j) o.h[j] = (bf16_t)((float)v.h[j] * m);
        *(uint4*)(dst + idx) = o.u;
    }
}

// ---------------------------------------------------------------------------
// K2a: score GEMM + exp.  S^T[t][gq] = sum_c kT[t][c] * Bsrc[gq][c].
// prescaled=1: Bsrc = Qmix (pure-copy staging).  prescaled=0: Bsrc = qT,
// scale applied during staging (fallback when ws is tight).
// ---------------------------------------------------------------------------
__global__ __launch_bounds__(256) void score_kernel(
    const bf16_t* __restrict__ kT,
    const bf16_t* __restrict__ Bsrc,
    const bf16_t* __restrict__ head_w,
    bf16_t* __restrict__ P,
    float* __restrict__ lbuf,
    float* __restrict__ l2buf,
    int prescaled)
{
    const int L  = blockIdx.x;
    const int b  = L & 7;
    const int n  = L >> 3;
    const int Mt = n & 7;
    const int Nt = n >> 3;
    const int Mbase = Mt * 128;
    const int Nbase = Nt * 128;
    const int g     = Nbase >> 10;
    const int qbase = Nbase & 1023;

    const int tid = threadIdx.x, lane = tid & 63, wid = tid >> 6;
    const int quad = lane >> 4, l16 = lane & 15;
    const int Msub = (wid & 1) * 64, Nsub = (wid >> 1) * 64;

    __shared__ __align__(16) bf16_t At[128 * 64];
    __shared__ __align__(16) bf16_t Bt[128 * 64];

    const bf16_t* kTb = kT + (size_t)b * TT * CC;
    // prescaled: Qmix plane (b,g) at row qbase; else raw qT plane b at row qbase
    const bf16_t* qrow = prescaled
        ? Bsrc + ((size_t)(b * NHH + g) * TT + qbase) * CC
        : Bsrc + ((size_t)b * TT + qbase) * CC;

    float smix6[6];
    #pragma unroll
    for (int h = 0; h < 6; ++h) smix6[h] = 0.125f * (float)head_w[g * 6 + h];

    f32x4 S[4][4];
    const f32x4 zero = {0.f, 0.f, 0.f, 0.f};
    #pragma unroll
    for (int mi = 0; mi < 4; ++mi)
        #pragma unroll
        for (int ni = 0; ni < 4; ++ni) S[mi][ni] = zero;

    for (int kk = 0; kk < 6; ++kk) {
        __syncthreads();
        #pragma unroll
        for (int it = 0; it < 4; ++it) {
            const int id = it * 256 + tid;
            const int row = id >> 3, ch = id & 7;
            U8 v; v.u = *(const uint4*)(kTb + (size_t)(Mbase + row) * CC + kk * 64 + ch * 8);
            *(uint4*)&At[row * 64 + ((ch ^ (row & 7)) * 8)] = v.u;
        }
        if (prescaled) {
            #pragma unroll
            for (int it = 0; it < 4; ++it) {
                const int id = it * 256 + tid;
                const int row = id >> 3, ch = id & 7;
                U8 v; v.u = *(const uint4*)(qrow + (size_t)row * CC + kk * 64 + ch * 8);
                *(uint4*)&Bt[row * 64 + ((ch ^ (row & 7)) * 8)] = v.u;
            }
        } else {
            const float m = smix6[kk];
            #pragma unroll
            for (int it = 0; it < 4; ++it) {
                const int id = it * 256 + tid;
                const int row = id >> 3, ch = id & 7;
                U8 v; v.u = *(const uint4*)(qrow + (size_t)row * CC + kk * 64 + ch * 8);
                U8 o;
                #pragma unroll
                for (int j = 0; j < 8; ++j) o.h[j] = (bf16_t)((float)v.h[j] * m);
                *(uint4*)&Bt[row * 64 + ((ch ^ (row & 7)) * 8)] = o.u;
            }
        }
        __syncthreads();
        #pragma unroll
        for (int k2 = 0; k2 < 2; ++k2) {
            const int sw = ((k2 * 4 + quad) ^ (l16 & 7)) * 8;
            bf16x8 a[4], bq[4];
            #pragma unroll
            for (int mi = 0; mi < 4; ++mi)
                a[mi] = *(const bf16x8*)&At[(Msub + mi * 16 + l16) * 64 + sw];
            #pragma unroll
            for (int ni = 0; ni < 4; ++ni)
                bq[ni] = *(const bf16x8*)&Bt[(Nsub + ni * 16 + l16) * 64 + sw];
            #pragma unroll
            for (int mi = 0; mi < 4; ++mi)
                #pragma unroll
                for (int ni = 0; ni < 4; ++ni)
                    S[mi][ni] = MFMA16(a[mi], bq[ni], S[mi][ni]);
        }
    }

    #pragma unroll
    for (int ni = 0; ni < 4; ++ni) {
        const int gq = Nbase + Nsub + ni * 16 + l16;
        float lsum = 0.f, l2sum = 0.f;
        #pragma unroll
        for (int mi = 0; mi < 4; ++mi) {
            float p[4];
            #pragma unroll
            for (int r = 0; r < 4; ++r) {
                p[r] = __expf(fminf(S[mi][ni][r], 60.0f));
                lsum += p[r]; l2sum += p[r] * p[r];
            }
            U2 lo2, hi2;
            lo2.h[0] = (bf16_t)p[0]; lo2.h[1] = (bf16_t)p[1];
            hi2.h[0] = (bf16_t)p[2]; hi2.h[1] = (bf16_t)p[3];
            uint2 pk; pk.x = lo2.u; pk.y = hi2.u;
            const size_t t = Mbase + Msub + mi * 16 + quad * 4;
            *(uint2*)(P + ((size_t)b * NGQ + gq) * TT + t) = pk;
        }
        lsum  += __shfl_xor(lsum, 16, 64);  lsum  += __shfl_xor(lsum, 32, 64);
        l2sum += __shfl_xor(l2sum, 16, 64); l2sum += __shfl_xor(l2sum, 32, 64);
        if (quad == 0) {
            atomicAdd(&lbuf[b * NGQ + gq], lsum);
            atomicAdd(&l2buf[b * NGQ + gq], l2sum);
        }
    }
}

// ---------------------------------------------------------------------------
// K2b: per-(b,g) InstanceNorm coefficients from row stats.
// ---------------------------------------------------------------------------
__global__ __launch_bounds__(256) void stats_kernel(
    const float* __restrict__ lbuf, const float* __restrict__ l2buf,
    const bf16_t* __restrict__ gamma, const bf16_t* __restrict__ beta,
    float* __restrict__ AcArr, float* __restrict__ CcArr)
{
    const int bg = blockIdx.x;
    const int base = (bg / 6) * NGQ + (bg % 6) * TT;
    const int tid = threadIdx.x;
    float c = 0.f;
    for (int i = tid; i < TT; i += 256) {
        const float lv = lbuf[base + i];
        c += l2buf[base + i] / (lv * lv);
    }
    #pragma unroll
    for (int off = 1; off < 64; off <<= 1) c += __shfl_xor(c, off, 64);
    __shared__ float red[4];
    if ((tid & 63) == 0) red[tid >> 6] = c;
    __syncthreads();
    if (tid == 0) {
        const float ss  = red[0] + red[1] + red[2] + red[3];
        const float var = fmaxf(ss - 1.0f, 0.0f) * (1.0f / 1048576.0f);
        const float A   = (float)gamma[bg % 6] * rsqrtf(var + 1e-5f);
        AcArr[bg] = A;
        CcArr[bg] = (float)beta[bg % 6] - A * (1.0f / 1024.0f);
    }
}

// ---------------------------------------------------------------------------
// K2c: PV + fused normalize/affine. Z stored at flat [NH][T][HD] offset:
//   Zb[b*393216 + g*65536 + q*64 + d]
// ---------------------------------------------------------------------------
__global__ __launch_bounds__(256) void pv_kernel(
    const bf16_t* __restrict__ P,
    const bf16_t* __restrict__ vm,
    const float* __restrict__ lbuf,
    const float* __restrict__ AcArr,
    const float* __restrict__ CcArr,
    const float* __restrict__ vrs,
    bf16_t* __restrict__ Zb)
{
    const int L  = blockIdx.x;
    const int b  = L & 7;
    const int n  = L >> 3;
    const int qt = n & 7;
    const int g  = n >> 3;
    const int qbase = qt * 128;
    const int tid = threadIdx.x, lane = tid & 63, wid = tid >> 6;
    const int quad = lane >> 4, l16 = lane & 15;
    const int Nsub = wid * 32;

    __shared__ __align__(16) bf16_t Pt[128 * 64];
    __shared__ __align__(16) bf16_t Vt[64 * 64];

    const bf16_t* Pb = P  + ((size_t)b * NGQ + g * TT + qbase) * TT;
    const bf16_t* Vb = vm + ((size_t)b * CC + g * 64) * TT;

    f32x4 U[4][2];
    const f32x4 zero = {0.f, 0.f, 0.f, 0.f};
    #pragma unroll
    for (int mi = 0; mi < 4; ++mi)
        #pragma unroll
        for (int ni = 0; ni < 2; ++ni) U[mi][ni] = zero;

    for (int tt = 0; tt < 16; ++tt) {
        __syncthreads();
        #pragma unroll
        for (int it = 0; it < 4; ++it) {
            const int id = it * 256 + tid;
            const int row = id >> 3, ch = id & 7;
            U8 v; v.u = *(const uint4*)(Pb + (size_t)row * TT + tt * 64 + ch * 8);
            *(uint4*)&Pt[row * 64 + ((ch ^ (row & 7)) * 8)] = v.u;
        }
        #pragma unroll
        for (int it = 0; it < 2; ++it) {
            const int id = it * 256 + tid;
            const int row = id >> 3, ch = id & 7;
            U8 v; v.u = *(const uint4*)(Vb + (size_t)row * TT + tt * 64 + ch * 8);
            *(uint4*)&Vt[row * 64 + ((ch ^ (row & 7)) * 8)] = v.u;
        }
        __syncthreads();
        #pragma unroll
        for (int k2 = 0; k2 < 2; ++k2) {
            const int sw = ((k2 * 4 + quad) ^ (l16 & 7)) * 8;
            bf16x8 a[4], bq[2];
            #pragma unroll
            for (int mi = 0; mi < 4; ++mi)
                a[mi] = *(const bf16x8*)&Vt[(mi * 16 + l16) * 64 + sw];
            #pragma unroll
            for (int ni = 0; ni < 2; ++ni)
                bq[ni] = *(const bf16x8*)&Pt[(Nsub + ni * 16 + l16) * 64 + sw];
            #pragma unroll
            for (int mi = 0; mi < 4; ++mi)
                #pragma unroll
                for (int ni = 0; ni < 2; ++ni)
                    U[mi][ni] = MFMA16(a[mi], bq[ni], U[mi][ni]);
        }
    }

    const float Acg = AcArr[b * NHH + g];
    const float Ccg = CcArr[b * NHH + g];
    bf16_t* Zbase = Zb + (size_t)b * TT * CC + (size_t)g * TT * 64;
    #pragma unroll
    for (int ni = 0; ni < 2; ++ni) {
        const int q = qbase + Nsub + ni * 16 + l16;
        const float invl = 1.0f / lbuf[b * NGQ + g * TT + q];
        #pragma unroll
        for (int mi = 0; mi < 4; ++mi) {
            f32x4 vr4 = *(const f32x4*)(vrs + (b * NHH + g) * 64 + mi * 16 + quad * 4);
            float z[4];
            #pragma unroll
            for (int r = 0; r < 4; ++r)
                z[r] = Acg * (U[mi][ni][r] * invl) + Ccg * vr4[r];
            U2 lo2, hi2;
            lo2.h[0] = (bf16_t)z[0]; lo2.h[1] = (bf16_t)z[1];
            hi2.h[0] = (bf16_t)z[2]; hi2.h[1] = (bf16_t)z[3];
            uint2 pk; pk.x = lo2.u; pk.y = hi2.u;
            *(uint2*)(Zbase + (size_t)q * 64 + mi * 16 + quad * 4) = pk;
        }
    }
}

// ---------------------------------------------------------------------------
// K3: projection.  out[b][o][t'] = projb[o] + sum_c Zb[t'][c]*projW[o][c]
// ---------------------------------------------------------------------------
__global__ __launch_bounds__(256) void proj_kernel(
    const bf16_t* __restrict__ Zb,
    const bf16_t* __restrict__ projW,
    const bf16_t* __restrict__ projb,
    float* __restrict__ out)
{
    const int ts = blockIdx.x;
    const int b  = blockIdx.y;
    const int t0 = ts * 32;
    const int tid = threadIdx.x, lane = tid & 63, wid = tid >> 6;
    const int quad = lane >> 4, l16 = lane & 15;

    __shared__ float pb[CC];
    for (int i = tid; i < CC; i += 256) pb[i] = (float)projb[i];
    __syncthreads();

    f32x4 acc[6][2];
    const f32x4 zero = {0.f, 0.f, 0.f, 0.f};
    #pragma unroll
    for (int mi = 0; mi < 6; ++mi)
        #pragma unroll
        for (int ni = 0; ni < 2; ++ni) acc[mi][ni] = zero;

    const bf16_t* Zbb = Zb + (size_t)b * TT * CC;
    for (int k0 = 0; k0 < CC; k0 += 32) {
        bf16x8 bfr[2];
        #pragma unroll
        for (int ni = 0; ni < 2; ++ni) {
            const int tl = t0 + ni * 16 + l16;
            bfr[ni] = *(const bf16x8*)(Zbb + (size_t)tl * CC + k0 + quad * 8);
        }
        #pragma unroll
        for (int mi = 0; mi < 6; ++mi) {
            const int o = wid * 96 + mi * 16 + l16;
            bf16x8 afr = *(const bf16x8*)(projW + (size_t)o * CC + k0 + quad * 8);
            #pragma unroll
            for (int ni = 0; ni < 2; ++ni)
                acc[mi][ni] = MFMA16(afr, bfr[ni], acc[mi][ni]);
        }
    }

    #pragma unroll
    for (int mi = 0; mi < 6; ++mi)
        #pragma unroll
        for (int ni = 0; ni < 2; ++ni)
            #pragma unroll
            for (int r = 0; r < 4; ++r) {
                const int o  = wid * 96 + mi * 16 + quad * 4 + r;
                const int tl = t0 + ni * 16 + l16;
                out[((size_t)b * CC + o) * TT + tl] = acc[mi][ni][r] + pb[o];
            }
}

// ---------------------------------------------------------------------------
extern "C" void kernel_launch(void* const* d_in, const int* in_sizes, int n_in,
                              void* d_out, int out_size, void* d_ws, size_t ws_size,
                              hipStream_t stream)
{
    float* outp = (float*)d_out;
    char* ws = (char*)d_ws;

    size_t off = 0;
    auto alloc = [&](size_t bytes) {
        void* p = ws + off;
        off += (bytes + 255) & ~(size_t)255;
        return p;
    };

    const size_t szQ = (size_t)BB * TT * CC * sizeof(bf16_t);   // 6 MB

    bf16_t* cx  = (bf16_t*)alloc(szQ);
    bf16_t* cWq = (bf16_t*)alloc((size_t)CC * CC * 2);
    bf16_t* cWk = (bf16_t*)alloc((size_t)CC * CC * 2);
    bf16_t* cWv = (bf16_t*)alloc((size_t)CC * CC * 2);
    bf16_t* cPW = (bf16_t*)alloc((size_t)CC * CC * 2);
    bf16_t* chw = (bf16_t*)alloc(64 * 2);
    bf16_t* cg  = (bf16_t*)alloc(64 * 2);
    bf16_t* cb  = (bf16_t*)alloc(64 * 2);
    bf16_t* cpb = (bf16_t*)alloc(CC * 2);
    bf16_t* qT  = (bf16_t*)alloc(szQ);
    bf16_t* kT  = (bf16_t*)alloc(szQ);
    bf16_t* vm  = (bf16_t*)alloc(szQ);
    bf16_t* P   = (bf16_t*)alloc((size_t)BB * NGQ * TT * 2);    // 96 MB
    float*  l12 = (float*)alloc((size_t)2 * BB * NGQ * 4);
    float*  lb  = l12;
    float*  l2b = l12 + (size_t)BB * NGQ;
    float*  vr  = (float*)alloc(48 * 64 * 4);
    float*  Ac  = (float*)alloc(48 * 4);
    float*  Cc  = (float*)alloc(48 * 4);
    bf16_t* Zb  = (bf16_t*)alloc(szQ);                          // 6 MB

    // optional prescaled-Qmix buffer (36 MB) — only if scratch allows
    const size_t qmixBytes = (size_t)BB * NHH * TT * CC * 2;
    const bool prescale = (off + qmixBytes + 256) <= ws_size;
    bf16_t* Qm = prescale ? (bf16_t*)alloc(qmixBytes) : nullptr;

    CastArgs ca;
    bf16_t* dsts[9] = {cx, cWq, cWk, cWv, chw, cg, cb, cPW, cpb};
    for (int i = 0; i < 9; ++i) {
        ca.src[i] = d_in[i];
        ca.dst[i] = dsts[i];
        ca.n[i]   = in_sizes[i];
    }

    hipMemsetAsync(l12, 0, (size_t)2 * BB * NGQ * 4, stream);
    cast_kernel<<<dim3(192, 9), 256, 0, stream>>>(ca);
    qkv_kernel<<<dim3(6, 16, 8), 256, 0, stream>>>(cx, cWq, cWk, cWv, qT, kT, vm);
    vrow_kernel<<<48, 256, 0, stream>>>(vm, vr);
    if (prescale) {
        qmix_kernel<<<dim3(48, 16), 256, 0, stream>>>(qT, chw, Qm);
        score_kernel<<<3072, 256, 0, stream>>>(kT, Qm, chw, P, lb, l2b, 1);
    } else {
        score_kernel<<<3072, 256, 0, stream>>>(kT, qT, chw, P, lb, l2b, 0);
    }
    stats_kernel<<<48, 256, 0, stream>>>(lb, l2b, cg, cb, Ac, Cc);
    pv_kernel<<<384, 256, 0, stream>>>(P, vm, lb, Ac, Cc, vr, Zb);
    proj_kernel<<<dim3(32, 8), 256, 0, stream>>>(Zb, cPW, cpb, outp);
}

// Round 9
// 217.651 us; speedup vs baseline: 1.0981x; 1.0981x over previous
//
#include <hip/hip_runtime.h>
#include <hip/hip_bf16.h>
#include <cstdint>

typedef __bf16 bf16_t;
typedef __bf16 bf16x8 __attribute__((ext_vector_type(8)));
typedef float  f32x4  __attribute__((ext_vector_type(4)));

#define MFMA16(a, b, c) __builtin_amdgcn_mfma_f32_16x16x32_bf16((a), (b), (c), 0, 0, 0)

constexpr int BB = 8, CC = 384, NHH = 6, TT = 1024;

union U8 { uint4 u; bf16_t h[8]; };
union U2 { unsigned int u; bf16_t h[2]; };

// ---------------------------------------------------------------------------
// K0: normalize all inputs to canonical bf16 (inputs fp32; probe kept).
// ---------------------------------------------------------------------------
struct CastArgs {
    const void* src[9];
    bf16_t*     dst[9];
    int         n[9];
};

__global__ __launch_bounds__(256) void cast_kernel(CastArgs a)
{
    const bool isbf = (((const unsigned short*)a.src[5])[0] == 0x3F80u);
    const int ai = blockIdx.y;
    const int n  = a.n[ai];
    bf16_t* dst  = a.dst[ai];
    const int t0     = (blockIdx.x * 256 + threadIdx.x) * 8;
    const int stride = gridDim.x * 256 * 8;
    if (isbf) {
        const bf16_t* s = (const bf16_t*)a.src[ai];
        for (int idx = t0; idx < n; idx += stride) {
            if (idx + 8 <= n) *(uint4*)(dst + idx) = *(const uint4*)(s + idx);
            else for (int j = 0; idx + j < n; ++j) dst[idx + j] = s[idx + j];
        }
    } else {
        const float* s = (const float*)a.src[ai];
        for (int idx = t0; idx < n; idx += stride) {
            if (idx + 8 <= n) {
                f32x4 v0 = *(const f32x4*)(s + idx);
                f32x4 v1 = *(const f32x4*)(s + idx + 4);
                U8 o;
                #pragma unroll
                for (int j = 0; j < 4; ++j) { o.h[j] = (bf16_t)v0[j]; o.h[4 + j] = (bf16_t)v1[j]; }
                *(uint4*)(dst + idx) = o.u;
            } else for (int j = 0; idx + j < n; ++j) dst[idx + j] = (bf16_t)s[idx + j];
        }
    }
}

// ---------------------------------------------------------------------------
// K1: QKV projection.
//  q branch (og 0,1): A=W (D rows=o) -> scale fp32 acc by 0.125*head_w[g][o/64]
//    and store 6 head-mixed copies Qmix[(b*6+g)][t][o] (b64 packed).
//  k branch (og 2,3): same orientation, store kT[b][t][o].
//  v branch (og 4,5): A=xT (D rows=t), store vm[b][o][t].
// ---------------------------------------------------------------------------
__global__ __launch_bounds__(256) void qkv_kernel(
    const bf16_t* __restrict__ x,
    const bf16_t* __restrict__ Wq,
    const bf16_t* __restrict__ Wk,
    const bf16_t* __restrict__ Wv,
    const bf16_t* __restrict__ head_w,
    bf16_t* __restrict__ Qmix,
    bf16_t* __restrict__ kT,
    bf16_t* __restrict__ vm)
{
    const int og = blockIdx.x;        // 0,1:q  2,3:k  4,5:v
    const int tt = blockIdx.y;
    const int b  = blockIdx.z;
    const int t0 = tt * 64;
    const int tid  = threadIdx.x;
    const int lane = tid & 63;
    const int wid  = tid >> 6;
    const int quad = lane >> 4;
    const int l16  = lane & 15;

    __shared__ __align__(16) bf16_t xT[64][CC + 8];
    __shared__ float smixL[36];

    if (tid < 36) smixL[tid] = 0.125f * (float)head_w[tid];
    {
        const bf16_t* xb = x + (size_t)b * CC * TT;
        const int tq = tid & 7;
        const int cp = tid >> 3;
        #pragma unroll
        for (int pass = 0; pass < 6; ++pass) {
            const int c = (pass * 32 + cp) * 2;
            U8 r0, r1;
            r0.u = *(const uint4*)(xb + (size_t)c * TT + t0 + tq * 8);
            r1.u = *(const uint4*)(xb + (size_t)(c + 1) * TT + t0 + tq * 8);
            #pragma unroll
            for (int j = 0; j < 8; ++j) {
                U2 p; p.h[0] = r0.h[j]; p.h[1] = r1.h[j];
                *(unsigned int*)&xT[tq * 8 + j][c] = p.u;
            }
        }
    }
    __syncthreads();

    const bf16_t* W = (og < 2) ? Wq : (og < 4) ? Wk : Wv;
    const int obase = (og & 1) * 192 + wid * 48;

    if (og < 4) {
        // A = W rows (m=o), B = xT rows (n=t)
        f32x4 acc[3][4];
        const f32x4 zero = {0.f, 0.f, 0.f, 0.f};
        #pragma unroll
        for (int mi = 0; mi < 3; ++mi)
            #pragma unroll
            for (int ni = 0; ni < 4; ++ni) acc[mi][ni] = zero;

        for (int k0 = 0; k0 < CC; k0 += 32) {
            bf16x8 afr[3];
            #pragma unroll
            for (int mi = 0; mi < 3; ++mi)
                afr[mi] = *(const bf16x8*)(W + (size_t)(obase + mi * 16 + l16) * CC + k0 + quad * 8);
            #pragma unroll
            for (int ni = 0; ni < 4; ++ni) {
                bf16x8 bfr = *(const bf16x8*)&xT[ni * 16 + l16][k0 + quad * 8];
                #pragma unroll
                for (int mi = 0; mi < 3; ++mi)
                    acc[mi][ni] = MFMA16(afr[mi], bfr, acc[mi][ni]);
            }
        }

        if (og < 2) {
            // 6 head-mixed copies, scaled in fp32 (single rounding)
            for (int g = 0; g < 6; ++g) {
                bf16_t* dst = Qmix + (size_t)(b * NHH + g) * TT * CC;
                #pragma unroll
                for (int mi = 0; mi < 3; ++mi)
                    #pragma unroll
                    for (int ni = 0; ni < 4; ++ni) {
                        const int o0 = obase + mi * 16 + quad * 4;
                        const int tl = t0 + ni * 16 + l16;
                        const float m = smixL[g * 6 + (o0 >> 6)];
                        U2 lo2, hi2;
                        lo2.h[0] = (bf16_t)(acc[mi][ni][0] * m); lo2.h[1] = (bf16_t)(acc[mi][ni][1] * m);
                        hi2.h[0] = (bf16_t)(acc[mi][ni][2] * m); hi2.h[1] = (bf16_t)(acc[mi][ni][3] * m);
                        uint2 pk; pk.x = lo2.u; pk.y = hi2.u;
                        *(uint2*)(dst + (size_t)tl * CC + o0) = pk;
                    }
            }
        } else {
            #pragma unroll
            for (int mi = 0; mi < 3; ++mi)
                #pragma unroll
                for (int ni = 0; ni < 4; ++ni) {
                    const int o0 = obase + mi * 16 + quad * 4;
                    const int tl = t0 + ni * 16 + l16;
                    U2 lo2, hi2;
                    lo2.h[0] = (bf16_t)acc[mi][ni][0]; lo2.h[1] = (bf16_t)acc[mi][ni][1];
                    hi2.h[0] = (bf16_t)acc[mi][ni][2]; hi2.h[1] = (bf16_t)acc[mi][ni][3];
                    uint2 pk; pk.x = lo2.u; pk.y = hi2.u;
                    *(uint2*)(kT + ((size_t)b * TT + tl) * CC + o0) = pk;
                }
        }
    } else {
        // A = xT (m=t), B = W (n=o): regs span t -> vm[o][t]
        f32x4 acc[4][3];
        const f32x4 zero = {0.f, 0.f, 0.f, 0.f};
        #pragma unroll
        for (int mi = 0; mi < 4; ++mi)
            #pragma unroll
            for (int ni = 0; ni < 3; ++ni) acc[mi][ni] = zero;

        for (int k0 = 0; k0 < CC; k0 += 32) {
            bf16x8 bfr[3];
            #pragma unroll
            for (int ni = 0; ni < 3; ++ni)
                bfr[ni] = *(const bf16x8*)(W + (size_t)(obase + ni * 16 + l16) * CC + k0 + quad * 8);
            #pragma unroll
            for (int mi = 0; mi < 4; ++mi) {
                bf16x8 afr = *(const bf16x8*)&xT[mi * 16 + l16][k0 + quad * 8];
                #pragma unroll
                for (int ni = 0; ni < 3; ++ni)
                    acc[mi][ni] = MFMA16(afr, bfr[ni], acc[mi][ni]);
            }
        }

        #pragma unroll
        for (int mi = 0; mi < 4; ++mi)
            #pragma unroll
            for (int ni = 0; ni < 3; ++ni) {
                const int ol  = obase + ni * 16 + l16;
                const int tl0 = mi * 16 + quad * 4;
                U2 lo2, hi2;
                lo2.h[0] = (bf16_t)acc[mi][ni][0]; lo2.h[1] = (bf16_t)acc[mi][ni][1];
                hi2.h[0] = (bf16_t)acc[mi][ni][2]; hi2.h[1] = (bf16_t)acc[mi][ni][3];
                uint2 pk; pk.x = lo2.u; pk.y = hi2.u;
                *(uint2*)(vm + ((size_t)b * CC + ol) * TT + t0 + tl0) = pk;
            }
    }
}

// ---------------------------------------------------------------------------
// K1b: vrs[b][g][d] = sum_t vm[b][g*64+d][t]
// ---------------------------------------------------------------------------
__global__ __launch_bounds__(256) void vrow_kernel(const bf16_t* __restrict__ vm,
                                                   float* __restrict__ vrs)
{
    const int bg = blockIdx.x;
    const int d  = threadIdx.x & 63;
    const int qr = threadIdx.x >> 6;
    const bf16_t* row = vm + ((size_t)(bg / 6) * CC + (bg % 6) * 64 + d) * TT + qr * 256;
    float s = 0.f;
    for (int i = 0; i < 256; i += 8) {
        U8 v; v.u = *(const uint4*)(row + i);
        #pragma unroll
        for (int j = 0; j < 8; ++j) s += (float)v.h[j];
    }
    __shared__ float red[4][64];
    red[qr][d] = s;
    __syncthreads();
    if (qr == 0) vrs[bg * 64 + d] = red[0][d] + red[1][d] + red[2][d] + red[3][d];
}

// ---------------------------------------------------------------------------
// K2: fused attention (flash-style, no P materialization).
// Block = (b, g, 64 q-rows). Per 128-t tile: score GEMM S^T=K·Qmix^T (R8's
// proven swizzled-LDS loop), exp in regs, P->LDS (b64, swizzled) in two
// 64-t halves, V-tile staged, PV accumulates U in regs. LDS union 24 KB:
// [At 16K | Bt 8K] reused as [Ps 8K | Vt 16K] after the kk loop.
// Epilogue: exact row l/l2 (block-local), Uhat=U/l fp32 + sumsq atomic.
// grid 768 = 3 blocks/CU, all resident.
// ---------------------------------------------------------------------------
__global__ __launch_bounds__(256, 3) void fused_attn(
    const bf16_t* __restrict__ Qmix,
    const bf16_t* __restrict__ kT,
    const bf16_t* __restrict__ vm,
    float* __restrict__ Uhat,
    float* __restrict__ sumsq)
{
    const int L  = blockIdx.x;
    const int b  = L & 7;              // XCD-pinned
    const int rr = L >> 3;
    const int qt = rr & 15;
    const int g  = rr >> 4;
    const int qbase = qt * 64;
    const int tid = threadIdx.x, lane = tid & 63, wid = tid >> 6;
    const int quad = lane >> 4, l16 = lane & 15;
    const int Msub = (wid & 1) * 64;       // score: t-half
    const int Nsub = (wid >> 1) * 32;      // score: q-half

    __shared__ __align__(16) bf16_t sm[12288];   // 24 KB union
    bf16_t* At = sm;              // [128][64] swizzled
    bf16_t* Bt = sm + 8192;       // [64][64]
    bf16_t* Ps = sm;              // [64][64]  (At space)
    bf16_t* Vt = sm + 4096;       // [64][128] (At tail + Bt space)
    __shared__ float lred[4][2][16], l2red[4][2][16];
    __shared__ float lrowS[64];

    const bf16_t* kTb = kT + (size_t)b * TT * CC;
    const bf16_t* Qb  = Qmix + ((size_t)(b * NHH + g) * TT + qbase) * CC;
    const bf16_t* Vb  = vm + ((size_t)b * CC + g * 64) * TT;

    float lacc[2] = {0.f, 0.f}, l2acc[2] = {0.f, 0.f};
    f32x4 U[4];
    const f32x4 zero = {0.f, 0.f, 0.f, 0.f};
    #pragma unroll
    for (int n2 = 0; n2 < 4; ++n2) U[n2] = zero;

    for (int tt = 0; tt < 8; ++tt) {
        // ---- scores: S^T tile (128 t x 64 q), wave owns (Msub 64t, Nsub 32q)
        f32x4 S[4][2];
        #pragma unroll
        for (int mi = 0; mi < 4; ++mi)
            #pragma unroll
            for (int ni = 0; ni < 2; ++ni) S[mi][ni] = zero;

        for (int kk = 0; kk < 6; ++kk) {
            __syncthreads();   // prior MFMA/PV reads of the union region done
            #pragma unroll
            for (int it = 0; it < 4; ++it) {          // At: K rows
                const int id = it * 256 + tid;
                const int row = id >> 3, ch = id & 7;
                U8 v; v.u = *(const uint4*)(kTb + (size_t)(tt * 128 + row) * CC + kk * 64 + ch * 8);
                *(uint4*)&At[row * 64 + ((ch ^ (row & 7)) * 8)] = v.u;
            }
            #pragma unroll
            for (int it = 0; it < 2; ++it) {          // Bt: Qmix rows (pure copy)
                const int id = it * 256 + tid;
                const int row = id >> 3, ch = id & 7;
                U8 v; v.u = *(const uint4*)(Qb + (size_t)row * CC + kk * 64 + ch * 8);
                *(uint4*)&Bt[row * 64 + ((ch ^ (row & 7)) * 8)] = v.u;
            }
            __syncthreads();
            #pragma unroll
            for (int k2 = 0; k2 < 2; ++k2) {
                const int sw = ((k2 * 4 + quad) ^ (l16 & 7)) * 8;
                bf16x8 a[4], bq[2];
                #pragma unroll
                for (int mi = 0; mi < 4; ++mi)
                    a[mi] = *(const bf16x8*)&At[(Msub + mi * 16 + l16) * 64 + sw];
                #pragma unroll
                for (int ni = 0; ni < 2; ++ni)
                    bq[ni] = *(const bf16x8*)&Bt[(Nsub + ni * 16 + l16) * 64 + sw];
                #pragma unroll
                for (int mi = 0; mi < 4; ++mi)
                    #pragma unroll
                    for (int ni = 0; ni < 2; ++ni)
                        S[mi][ni] = MFMA16(a[mi], bq[ni], S[mi][ni]);
            }
        }

        // ---- exp in place + row partials
        #pragma unroll
        for (int mi = 0; mi < 4; ++mi)
            #pragma unroll
            for (int ni = 0; ni < 2; ++ni)
                #pragma unroll
                for (int r = 0; r < 4; ++r) {
                    const float p = __expf(fminf(S[mi][ni][r], 60.0f));
                    S[mi][ni][r] = p;
                    lacc[ni]  += p;
                    l2acc[ni] += p * p;
                }

        __syncthreads();   // At/Bt dead -> safe to overwrite with Vt/Ps

        // ---- stage V tile (64 d x 128 t, swizzled)
        #pragma unroll
        for (int it = 0; it < 4; ++it) {
            const int id = it * 256 + tid;
            const int row = id >> 4, ch = id & 15;
            U8 v; v.u = *(const uint4*)(Vb + (size_t)row * TT + tt * 128 + ch * 8);
            *(uint4*)&Vt[row * 128 + ((((ch & 7) ^ (row & 7)) | (ch & 8)) * 8)] = v.u;
        }

        // ---- two PV halves; Ps written by the waves owning that t-half
        #pragma unroll
        for (int h = 0; h < 2; ++h) {
            if ((wid & 1) == h) {
                #pragma unroll
                for (int mi = 0; mi < 4; ++mi) {
                    const int tc = mi * 2 + (quad >> 1);
                    #pragma unroll
                    for (int ni = 0; ni < 2; ++ni) {
                        const int q = Nsub + ni * 16 + l16;
                        U2 lo2, hi2;
                        lo2.h[0] = (bf16_t)S[mi][ni][0]; lo2.h[1] = (bf16_t)S[mi][ni][1];
                        hi2.h[0] = (bf16_t)S[mi][ni][2]; hi2.h[1] = (bf16_t)S[mi][ni][3];
                        uint2 pk; pk.x = lo2.u; pk.y = hi2.u;
                        *(uint2*)&Ps[q * 64 + ((tc ^ (l16 & 7)) * 8) + (quad & 1) * 4] = pk;
                    }
                }
            }
            __syncthreads();   // Ps(h) + Vt ready
            // PV: wave owns q in [wid*16, wid*16+16), all 64 d
            bf16x8 ap[2];
            #pragma unroll
            for (int k2 = 0; k2 < 2; ++k2) {
                const int qa = wid * 16 + l16;
                ap[k2] = *(const bf16x8*)&Ps[qa * 64 + (((k2 * 4 + quad) ^ (l16 & 7)) * 8)];
            }
            #pragma unroll
            for (int n2 = 0; n2 < 4; ++n2) {
                const int d = n2 * 16 + l16;
                #pragma unroll
                for (int k2 = 0; k2 < 2; ++k2) {
                    const int tc = h * 8 + k2 * 4 + quad;
                    bf16x8 bv = *(const bf16x8*)&Vt[d * 128 + ((((tc & 7) ^ (l16 & 7)) | (tc & 8)) * 8)];
                    U[n2] = MFMA16(ap[k2], bv, U[n2]);
                }
            }
            __syncthreads();   // PV(h) reads done before Ps overwrite / next tt
        }
    }

    // ---- row stats: reduce over quad (lanes share q at fixed l16)
    #pragma unroll
    for (int ni = 0; ni < 2; ++ni) {
        float l = lacc[ni], l2 = l2acc[ni];
        l  += __shfl_xor(l, 16, 64);  l  += __shfl_xor(l, 32, 64);
        l2 += __shfl_xor(l2, 16, 64); l2 += __shfl_xor(l2, 32, 64);
        if (quad == 0) { lred[wid][ni][l16] = l; l2red[wid][ni][l16] = l2; }
    }
    __syncthreads();
    if (tid < 64) {
        const int q = tid;
        const int w0 = (q >> 5) * 2, ni = (q >> 4) & 1, lo = q & 15;
        const float l  = lred[w0][ni][lo]  + lred[w0 + 1][ni][lo];
        const float l2 = l2red[w0][ni][lo] + l2red[w0 + 1][ni][lo];
        lrowS[q] = l;
        float c = l2 / (l * l);
        #pragma unroll
        for (int off = 1; off < 64; off <<= 1) c += __shfl_xor(c, off, 64);
        if (tid == 0) atomicAdd(&sumsq[b * NHH + g], c);
    }
    __syncthreads();

    // ---- Uhat = U / l  (fp32, flat [b][g][q][d])
    float* Ub = Uhat + ((size_t)(b * NHH + g) * TT + qbase) * 64;
    #pragma unroll
    for (int r = 0; r < 4; ++r) {
        const int ql = wid * 16 + quad * 4 + r;
        const float invl = 1.0f / lrowS[ql];
        #pragma unroll
        for (int n2 = 0; n2 < 4; ++n2)
            Ub[(size_t)ql * 64 + n2 * 16 + l16] = U[n2][r] * invl;
    }
}

// ---------------------------------------------------------------------------
// K3: projection + fused InstanceNorm affine + bias + transpose (R4-proven).
//   Z[t'][c'] = Ac[h]*Uhat_flat[off] + Cc[h]*vrs[h][d], off=t'*384+c'
// ---------------------------------------------------------------------------
__global__ __launch_bounds__(256) void proj_kernel(
    const float* __restrict__ Uhat,
    const float* __restrict__ vrs,
    const float* __restrict__ sumsq,
    const bf16_t* __restrict__ gamma,
    const bf16_t* __restrict__ beta,
    const bf16_t* __restrict__ projW,
    const bf16_t* __restrict__ projb,
    float* __restrict__ out)
{
    const int ts = blockIdx.x;
    const int b  = blockIdx.y;
    const int t0 = ts * 32;
    const int tid = threadIdx.x, lane = tid & 63, wid = tid >> 6;
    const int quad = lane >> 4, l16 = lane & 15;

    __shared__ float Ac[6], Cc[6], pb[CC];
    if (tid < 6) {
        const float ss  = sumsq[b * NHH + tid];
        const float var = fmaxf(ss - 1.0f, 0.0f) * (1.0f / 1048576.0f);
        const float a   = (float)gamma[tid] * rsqrtf(var + 1e-5f);
        Ac[tid] = a;
        Cc[tid] = (float)beta[tid] - a * (1.0f / 1024.0f);
    }
    for (int i = tid; i < CC; i += 256) pb[i] = (float)projb[i];
    __syncthreads();

    f32x4 acc[6][2];
    const f32x4 zero = {0.f, 0.f, 0.f, 0.f};
    #pragma unroll
    for (int mi = 0; mi < 6; ++mi)
        #pragma unroll
        for (int ni = 0; ni < 2; ++ni) acc[mi][ni] = zero;

    const float* Ub = Uhat + (size_t)b * TT * CC;
    for (int k0 = 0; k0 < CC; k0 += 32) {
        bf16x8 bfr[2];
        #pragma unroll
        for (int ni = 0; ni < 2; ++ni) {
            const int tl = t0 + ni * 16 + l16;
            const int baseoff = tl * CC + k0 + quad * 8;
            f32x4 u0 = *(const f32x4*)(Ub + baseoff);
            f32x4 u1 = *(const f32x4*)(Ub + baseoff + 4);
            U8 z;
            #pragma unroll
            for (int j = 0; j < 8; ++j) {
                const int off = baseoff + j;
                const int h = off >> 16;
                const int d = off & 63;
                const float uv = (j < 4) ? u0[j] : u1[j - 4];
                z.h[j] = (bf16_t)(Ac[h] * uv + Cc[h] * vrs[(b * NHH + h) * 64 + d]);
            }
            bfr[ni] = *(const bf16x8*)&z;
        }
        #pragma unroll
        for (int mi = 0; mi < 6; ++mi) {
            const int o = wid * 96 + mi * 16 + l16;
            bf16x8 afr = *(const bf16x8*)(projW + (size_t)o * CC + k0 + quad * 8);
            #pragma unroll
            for (int ni = 0; ni < 2; ++ni)
                acc[mi][ni] = MFMA16(afr, bfr[ni], acc[mi][ni]);
        }
    }

    #pragma unroll
    for (int mi = 0; mi < 6; ++mi)
        #pragma unroll
        for (int ni = 0; ni < 2; ++ni)
            #pragma unroll
            for (int r = 0; r < 4; ++r) {
                const int o  = wid * 96 + mi * 16 + quad * 4 + r;
                const int tl = t0 + ni * 16 + l16;
                out[((size_t)b * CC + o) * TT + tl] = acc[mi][ni][r] + pb[o];
            }
}

// ---------------------------------------------------------------------------
extern "C" void kernel_launch(void* const* d_in, const int* in_sizes, int n_in,
                              void* d_out, int out_size, void* d_ws, size_t ws_size,
                              hipStream_t stream)
{
    float* outp = (float*)d_out;
    char* ws = (char*)d_ws;

    size_t off = 0;
    auto alloc = [&](size_t bytes) {
        void* p = ws + off;
        off += (bytes + 255) & ~(size_t)255;
        return p;
    };

    const size_t szQ = (size_t)BB * TT * CC * sizeof(bf16_t);   // 6 MB

    bf16_t* cx  = (bf16_t*)alloc(szQ);
    bf16_t* cWq = (bf16_t*)alloc((size_t)CC * CC * 2);
    bf16_t* cWk = (bf16_t*)alloc((size_t)CC * CC * 2);
    bf16_t* cWv = (bf16_t*)alloc((size_t)CC * CC * 2);
    bf16_t* cPW = (bf16_t*)alloc((size_t)CC * CC * 2);
    bf16_t* chw = (bf16_t*)alloc(64 * 2);
    bf16_t* cg  = (bf16_t*)alloc(64 * 2);
    bf16_t* cb  = (bf16_t*)alloc(64 * 2);
    bf16_t* cpb = (bf16_t*)alloc(CC * 2);
    bf16_t* Qm  = (bf16_t*)alloc((size_t)BB * NHH * TT * CC * 2);  // 37.7 MB
    bf16_t* kT  = (bf16_t*)alloc(szQ);
    bf16_t* vm  = (bf16_t*)alloc(szQ);
    float*  Uh  = (float*)alloc((size_t)BB * NHH * TT * 64 * 4);   // 12.6 MB
    float*  vr  = (float*)alloc(48 * 64 * 4);
    float*  sq  = (float*)alloc(48 * 4);

    CastArgs ca;
    bf16_t* dsts[9] = {cx, cWq, cWk, cWv, chw, cg, cb, cPW, cpb};
    for (int i = 0; i < 9; ++i) {
        ca.src[i] = d_in[i];
        ca.dst[i] = dsts[i];
        ca.n[i]   = in_sizes[i];
    }

    hipMemsetAsync(sq, 0, 48 * sizeof(float), stream);
    cast_kernel<<<dim3(192, 9), 256, 0, stream>>>(ca);
    qkv_kernel<<<dim3(6, 16, 8), 256, 0, stream>>>(cx, cWq, cWk, cWv, chw, Qm, kT, vm);
    vrow_kernel<<<48, 256, 0, stream>>>(vm, vr);
    fused_attn<<<768, 256, 0, stream>>>(Qm, kT, vm, Uh, sq);
    proj_kernel<<<dim3(32, 8), 256, 0, stream>>>(Uh, vr, sq, cg, cb, cPW, cpb, outp);
}